// Round 9
// baseline (114.011 us; speedup 1.0000x reference)
//
#include <hip/hip_runtime.h>
#include <hip/hip_bf16.h>

// LSS voxel pooling: prep (softmax+transpose) -> 512-bucket scatter (16-pixel
// blocks, batch-local 256-bin histograms) -> in-LDS-sort register gather.
// Lessons: r1 global f32 atomics op-bound; r4 random 8B scatter 8x write-amp;
// r7 bulk LDS f32 atomics ~3cy/lane serialized; r8 132-block scatter starves
// occupancy. B=2, N=6, D=112, H=16, W=44, C=80, BEV 128x128.

constexpr int B = 2, N = 6, D = 112, H = 16, W = 44, C = 80;
constexpr int HW = H * W;            // 704
constexpr int NPIX = B * N * HW;     // 8448
constexpr int NV = 128 * 128;        // 16384
constexpr int PTS = NPIX * D;        // 946176
constexpr int DHW = D * HW;          // 78848
constexpr int NBKT = 512;            // global buckets (64 voxel-bins each)
constexpr int CAP = 2816;            // per-bucket capacity (mean 1848, +22 sigma)

__global__ __launch_bounds__(NBKT) void init_cursor_kernel(
    int* __restrict__ cursor) {
  cursor[threadIdx.x] = threadIdx.x * CAP;
}

// ---- prep: ctx transpose + softmax -> probD[bn][d][hw] (gidx layout) ----
// block = 64 consecutive pixels of one camera, 256 threads (4 d-groups x 28).
__global__ __launch_bounds__(256) void prep_kernel(
    const float* __restrict__ logits, const float* __restrict__ ctx,
    float* __restrict__ probD, float* __restrict__ ctxT) {
  const int t = threadIdx.x;
  const int pix0 = blockIdx.x * 64;
  const int bn = pix0 / HW;
  const int hw0 = pix0 - bn * HW;

  __shared__ float tile[C][65];
  __shared__ float redm[4][64], reds[4][64];

  // ctx transpose (strided load -> LDS -> coalesced store)
  const float* src = ctx + (size_t)bn * C * HW + hw0;
#pragma unroll
  for (int it = 0; it < (C * 64) / 256; ++it) {
    const int idx = it * 256 + t;
    const int c = idx >> 6;
    const int i = idx & 63;
    tile[c][i] = src[(size_t)c * HW + i];
  }
  __syncthreads();
  {
    float* dst = ctxT + (size_t)pix0 * C;
#pragma unroll
    for (int it = 0; it < (C * 64) / 256; ++it) {
      const int j = it * 256 + t;
      const int pl = j / C;
      const int c = j - pl * C;
      dst[j] = tile[c][pl];
    }
  }

  // softmax over D, 28 logits per thread in registers
  const int l = t & 63;
  const int q = t >> 6;
  const int hw = hw0 + l;
  const int d0 = q * 28;
  const float* lg = logits + (size_t)bn * DHW + hw;

  float x[28];
  float m = -3.0e38f;
#pragma unroll
  for (int j = 0; j < 28; ++j) {
    x[j] = lg[(size_t)(d0 + j) * HW];   // coalesced
    m = fmaxf(m, x[j]);
  }
  redm[q][l] = m;
  __syncthreads();
  m = fmaxf(fmaxf(redm[0][l], redm[1][l]), fmaxf(redm[2][l], redm[3][l]));
  float s = 0.0f;
#pragma unroll
  for (int j = 0; j < 28; ++j) {
    x[j] = __expf(x[j] - m);
    s += x[j];
  }
  reds[q][l] = s;
  __syncthreads();
  const float inv =
      1.0f / (reds[0][l] + reds[1][l] + reds[2][l] + reds[3][l]);

  float* pd = probD + (size_t)bn * DHW + hw;
#pragma unroll
  for (int j = 0; j < 28; ++j) pd[(size_t)(d0 + j) * HW] = x[j] * inv;
}

// ---- bucket scatter: 528 blocks (16 pixels x 112 d), 256-bin local hist ----
__global__ __launch_bounds__(256) void bucket_scatter_kernel(
    const float* __restrict__ probD, const int* __restrict__ gidx,
    int* __restrict__ cursor, uint2* __restrict__ sorted) {
  const int t = threadIdx.x;
  const int blk = blockIdx.x;        // bn * 44 + chunk
  const int bn = blk / 44;
  const int hw0 = (blk - bn * 44) * 16;
  const int b = bn / N;
  const int pix0 = bn * HW + hw0;

  __shared__ int hist[256], sbase[256];
  hist[t] = 0;
  __syncthreads();

  const int l = t & 15;              // pixel lane
  const int q = t >> 4;              // d-group (16 groups x 7 d)
  const size_t base = (size_t)bn * DHW + hw0 + l;

  unsigned w0[7];
  int rank[7];
  float pv[7];
#pragma unroll
  for (int j = 0; j < 7; ++j) {
    const int d = q * 7 + j;
    const int fb = b * NV + gidx[base + (size_t)d * HW];   // 64B segments
    pv[j] = probD[base + (size_t)d * HW];
    w0[j] = (unsigned)(pix0 + l) | ((unsigned)fb << 16);
    rank[j] = atomicAdd(&hist[(w0[j] >> 22) & 255], 1);    // local-bucket rank
  }
  __syncthreads();

  // reserve per-bucket global ranges (256 atomics/block)
  {
    const int c_ = hist[t];
    sbase[t] = c_ ? atomicAdd(&cursor[(b << 8) | t], c_) : 0;
  }
  __syncthreads();

  // clustered record writes (runs of ~7 -> ~1 line per run, single burst)
#pragma unroll
  for (int j = 0; j < 7; ++j) {
    const int gb = w0[j] >> 22;
    const int lb = gb & 255;
    const int pos = sbase[lb] + rank[j];
    if (pos < (gb + 1) * CAP)   // statistically unreachable guard
      sorted[pos] = make_uint2(w0[j], __float_as_uint(pv[j]));
  }
}

// ---- bucket gather: in-LDS voxel sort, register accumulation ----
// block g: batch b=g>>8, voxels (g&255)*64..+64. 512 threads = 8 waves.
__global__ __launch_bounds__(512) void bucket_gather_kernel(
    const float* __restrict__ ctxT, const uint2* __restrict__ sorted,
    const int* __restrict__ cursor, float* __restrict__ out) {
  const int t = threadIdx.x;
  const int g = blockIdx.x;
  const int b = g >> 8;
  const int vox0 = (g & 255) * 64;

  __shared__ uint2 srec[CAP];        // voxel-sorted records
  __shared__ float tile[64][80];     // output tile
  __shared__ int shist[64], soff[64];

  if (t < 64) shist[t] = 0;
  __syncthreads();

  int cnt = cursor[g] - g * CAP;
  if (cnt > CAP) cnt = CAP;
  const uint2* rec = sorted + (size_t)g * CAP;

  uint2 rr[6];
  int rk[6];
#pragma unroll
  for (int k = 0; k < 6; ++k) {
    const int idx = t + k * 512;
    rk[k] = -1;
    if (idx < cnt) {
      rr[k] = rec[idx];                                  // coalesced
      rk[k] = atomicAdd(&shist[(rr[k].x >> 16) & 63], 1);
    }
  }
  __syncthreads();

  if (t < 64) {
    const int v = shist[t];
    int xx = v;
#pragma unroll
    for (int o = 1; o < 64; o <<= 1) {
      const int y = __shfl_up(xx, o, 64);
      if (t >= o) xx += y;
    }
    soff[t] = xx - v;
  }
  __syncthreads();

#pragma unroll
  for (int k = 0; k < 6; ++k) {
    if (rk[k] >= 0) {
      const int v = (rr[k].x >> 16) & 63;
      srec[soff[v] + rk[k]] = rr[k];
    }
  }
  __syncthreads();

  const int w = t >> 6;
  const int l = t & 63;
  for (int j = 0; j < 8; ++j) {
    const int v = w * 8 + j;
    const int s0 = soff[v];
    const int n = shist[v];
    float a0 = 0.0f, a1 = 0.0f;
    int k = 0;
    for (; k + 4 <= n; k += 4) {
      const uint2 ra = srec[s0 + k + 0];
      const uint2 rb = srec[s0 + k + 1];
      const uint2 rc = srec[s0 + k + 2];
      const uint2 rd = srec[s0 + k + 3];
      const float* wa = ctxT + (size_t)(ra.x & 0xFFFFu) * C;
      const float* wb = ctxT + (size_t)(rb.x & 0xFFFFu) * C;
      const float* wc = ctxT + (size_t)(rc.x & 0xFFFFu) * C;
      const float* wd = ctxT + (size_t)(rd.x & 0xFFFFu) * C;
      const float pa = __uint_as_float(ra.y);
      const float pb = __uint_as_float(rb.y);
      const float pc = __uint_as_float(rc.y);
      const float pd = __uint_as_float(rd.y);
      a0 += pa * wa[l];
      a0 += pb * wb[l];
      a0 += pc * wc[l];
      a0 += pd * wd[l];
      if (l < 16) {
        a1 += pa * wa[64 + l];
        a1 += pb * wb[64 + l];
        a1 += pc * wc[64 + l];
        a1 += pd * wd[64 + l];
      }
    }
    for (; k < n; ++k) {
      const uint2 ra = srec[s0 + k];
      const float* wa = ctxT + (size_t)(ra.x & 0xFFFFu) * C;
      const float pa = __uint_as_float(ra.y);
      a0 += pa * wa[l];
      if (l < 16) a1 += pa * wa[64 + l];
    }
    tile[v][l] = a0;
    if (l < 16) tile[v][64 + l] = a1;
  }
  __syncthreads();

  const size_t ob = (size_t)b * C * NV + vox0;
#pragma unroll
  for (int i = 0; i < 10; ++i) {
    const int idx = i * 512 + t;
    const int c = idx >> 6;
    const int v = idx & 63;
    out[ob + (size_t)c * NV + v] = tile[v][c];
  }
}

// ---- fallback: direct channel-major atomics (out must be zeroed) ----
__global__ __launch_bounds__(256) void lift_splat_direct_kernel(
    const float* __restrict__ logits, const float* __restrict__ ctx,
    const int* __restrict__ gidx, float* __restrict__ out) {
  const int t = threadIdx.x;
  const int pix = blockIdx.x;
  const int hw = pix % HW;
  const int bn = pix / HW;
  const int b = bn / N;

  const float* lg = logits + (size_t)bn * DHW + hw;
  const int* gi = gidx + (size_t)bn * DHW + hw;
  const float* cx = ctx + (size_t)bn * (C * HW) + hw;

  __shared__ float s_prob[D];
  __shared__ float s_ctx[C];
  __shared__ int s_idx[D];
  __shared__ float red[256];

  float v = -3.0e38f;
  if (t < D) {
    v = lg[(size_t)t * HW];
    s_idx[t] = gi[(size_t)t * HW];
  }
  if (t < C) s_ctx[t] = cx[(size_t)t * HW];

  red[t] = v;
  __syncthreads();
#pragma unroll
  for (int s = 128; s >= 1; s >>= 1) {
    if (t < s) red[t] = fmaxf(red[t], red[t + s]);
    __syncthreads();
  }
  const float m = red[0];
  __syncthreads();

  const float e = (t < D) ? __expf(v - m) : 0.0f;
  red[t] = e;
  __syncthreads();
#pragma unroll
  for (int s = 128; s >= 1; s >>= 1) {
    if (t < s) red[t] += red[t + s];
    __syncthreads();
  }
  const float inv = 1.0f / red[0];
  if (t < D) s_prob[t] = e * inv;
  __syncthreads();

  for (int f = t; f < D * C; f += 256) {
    const int d = f / C;
    const int c = f - d * C;
    atomicAdd(&out[((size_t)(b * C + c)) * NV + s_idx[d]],
              s_prob[d] * s_ctx[c]);
  }
}

extern "C" void kernel_launch(void* const* d_in, const int* in_sizes, int n_in,
                              void* d_out, int out_size, void* d_ws,
                              size_t ws_size, hipStream_t stream) {
  const float* logits = (const float*)d_in[0];
  const float* ctx = (const float*)d_in[1];
  const int* gidx = (const int*)d_in[2];
  float* out = (float*)d_out;

  size_t off = 0;
  uint2* sorted = (uint2*)((char*)d_ws + off);
  off += (size_t)NBKT * CAP * sizeof(uint2);             // 11,534,336
  float* probD = (float*)((char*)d_ws + off);
  off += (size_t)PTS * sizeof(float);                    //  3,784,704
  float* ctxT = (float*)((char*)d_ws + off);
  off += (size_t)NPIX * C * sizeof(float);               //  2,703,360
  int* cursor = (int*)((char*)d_ws + off);
  off += (size_t)NBKT * sizeof(int);                     // ~18 MB total

  if (ws_size >= off) {
    init_cursor_kernel<<<1, NBKT, 0, stream>>>(cursor);
    prep_kernel<<<NPIX / 64, 256, 0, stream>>>(logits, ctx, probD, ctxT);
    bucket_scatter_kernel<<<B * N * (HW / 16), 256, 0, stream>>>(
        probD, gidx, cursor, sorted);
    bucket_gather_kernel<<<NBKT, 512, 0, stream>>>(ctxT, sorted, cursor, out);
  } else {
    (void)hipMemsetAsync(d_out, 0, (size_t)out_size * sizeof(float), stream);
    lift_splat_direct_kernel<<<NPIX, 256, 0, stream>>>(logits, ctx, gidx, out);
  }
}

// Round 10
// 102.976 us; speedup vs baseline: 1.1072x; 1.1072x over previous
//
#include <hip/hip_runtime.h>
#include <hip/hip_bf16.h>

// LSS voxel pooling: ctxT transpose -> fused softmax+LDS-sorted bucket scatter
// -> in-LDS-sort register gather. Lessons: r1 global f32 atomics op-bound;
// r4 random 8B scatter 8x write-amp; r7 bulk LDS f32 atomics serialize
// (~3cy/lane); r9 scatter occupancy neutral -> cut latency+traffic+dispatches.
// B=2, N=6, D=112, H=16, W=44, C=80, BEV 128x128.

constexpr int B = 2, N = 6, D = 112, H = 16, W = 44, C = 80;
constexpr int HW = H * W;            // 704
constexpr int NPIX = B * N * HW;     // 8448
constexpr int NV = 128 * 128;        // 16384
constexpr int PTS = NPIX * D;        // 946176
constexpr int DHW = D * HW;          // 78848
constexpr int NBKT = 512;            // global buckets (64 voxel-bins each)
constexpr int CAP = 2816;            // per-bucket capacity (mean 1848, +22 sigma)
constexpr int RPB = 16 * D;          // records per scatter block = 1792

// ---- pass 1: ctx transpose (+ cursor zeroing in first 2 blocks) ----
__global__ __launch_bounds__(256) void ctxT_kernel(
    const float* __restrict__ ctx, float* __restrict__ ctxT,
    int* __restrict__ cursor) {
  const int t = threadIdx.x;
  if (blockIdx.x < 2) cursor[blockIdx.x * 256 + t] = 0;

  __shared__ float tile[C][65];
  const int pix0 = blockIdx.x * 64;
  const int bn = pix0 / HW;
  const int hw0 = pix0 - bn * HW;

  const float* src = ctx + (size_t)bn * C * HW + hw0;
#pragma unroll
  for (int it = 0; it < (C * 64) / 256; ++it) {
    const int idx = it * 256 + t;
    const int c = idx >> 6;
    const int i = idx & 63;
    tile[c][i] = src[(size_t)c * HW + i];
  }
  __syncthreads();
  float* dst = ctxT + (size_t)pix0 * C;
#pragma unroll
  for (int it = 0; it < (C * 64) / 256; ++it) {
    const int j = it * 256 + t;
    const int pl = j / C;
    const int c = j - pl * C;
    dst[j] = tile[c][pl];
  }
}

// ---- pass 2: fused softmax + bucketed scatter with LDS-sorted dump ----
// block = 16 pixels x 112 d (1792 records), 256 threads: l=t&15 pixel,
// q=t>>4 d-group of 7.
__global__ __launch_bounds__(256) void scatter_kernel(
    const float* __restrict__ logits, const int* __restrict__ gidx,
    int* __restrict__ cursor, uint2* __restrict__ sorted) {
  const int t = threadIdx.x;
  const int blk = blockIdx.x;        // bn * 44 + chunk
  const int bn = blk / 44;
  const int hw0 = (blk - bn * 44) * 16;
  const int b = bn / N;
  const int pix0 = bn * HW + hw0;

  __shared__ float redm[16][17], reds[16][17];
  __shared__ int hist[256], sbase[256], soff[256];
  __shared__ int wsum[4];
  __shared__ uint2 srec[RPB];        // 14336 B

  hist[t] = 0;

  const int l = t & 15;
  const int q = t >> 4;
  const size_t base = (size_t)bn * DHW + hw0 + l;

  // softmax over D: 7 logits/thread, 16-group LDS reduce per pixel
  float x[7];
  float m = -3.0e38f;
#pragma unroll
  for (int j = 0; j < 7; ++j) {
    x[j] = logits[base + (size_t)(q * 7 + j) * HW];   // 64B segments
    m = fmaxf(m, x[j]);
  }
  redm[l][q] = m;
  __syncthreads();
#pragma unroll
  for (int qq = 0; qq < 16; ++qq) m = fmaxf(m, redm[l][qq]);
  float s = 0.0f;
#pragma unroll
  for (int j = 0; j < 7; ++j) {
    x[j] = __expf(x[j] - m);
    s += x[j];
  }
  reds[l][q] = s;
  __syncthreads();
  s = 0.0f;
#pragma unroll
  for (int qq = 0; qq < 16; ++qq) s += reds[l][qq];
  const float inv = 1.0f / s;

  // records + block-local rank
  unsigned w0[7];
  int rank[7];
#pragma unroll
  for (int j = 0; j < 7; ++j) {
    const int fb = b * NV + gidx[base + (size_t)(q * 7 + j) * HW];
    w0[j] = (unsigned)(pix0 + l) | ((unsigned)fb << 16);
    x[j] *= inv;
    rank[j] = atomicAdd(&hist[(w0[j] >> 22) & 255], 1);
  }
  __syncthreads();

  // exclusive scan over 256 bins (4-wave shfl scan)
  const int hv = hist[t];
  int xx = hv;
#pragma unroll
  for (int o = 1; o < 64; o <<= 1) {
    const int y = __shfl_up(xx, o, 64);
    if ((t & 63) >= o) xx += y;
  }
  if ((t & 63) == 63) wsum[t >> 6] = xx;
  // reserve global range for this block's bucket run (256 atomics)
  sbase[t] = hv ? atomicAdd(&cursor[(b << 8) | t], hv) : 0;
  __syncthreads();
  int woff = 0;
#pragma unroll
  for (int ww = 0; ww < 4; ++ww)
    if (ww < (t >> 6)) woff += wsum[ww];
  soff[t] = woff + xx - hv;          // exclusive prefix for bin t
  __syncthreads();

  // place records bucket-sorted in LDS
#pragma unroll
  for (int j = 0; j < 7; ++j) {
    const int lb = (w0[j] >> 22) & 255;
    srec[soff[lb] + rank[j]] = make_uint2(w0[j], __float_as_uint(x[j]));
  }
  __syncthreads();

  // dump: consecutive slots -> same-bucket runs -> coalesced-ish stores
  for (int s_ = t; s_ < RPB; s_ += 256) {
    const uint2 r = srec[s_];
    const int gb = (r.x >> 22) & 511;
    const int lb = gb & 255;
    const int posin = sbase[lb] + (s_ - soff[lb]);
    if (posin < CAP)                 // statistically unreachable guard
      sorted[(size_t)gb * CAP + posin] = r;
  }
}

// ---- pass 3: bucket gather, in-LDS voxel sort, register accumulation ----
// block g: b=g>>8, voxels (g&255)*64..+64. 1024 threads = 16 waves x 4 vox.
__global__ __launch_bounds__(1024) void gather_kernel(
    const float* __restrict__ ctxT, const uint2* __restrict__ sorted,
    const int* __restrict__ cursor, float* __restrict__ out) {
  const int t = threadIdx.x;
  const int g = blockIdx.x;
  const int b = g >> 8;
  const int vox0 = (g & 255) * 64;

  __shared__ uint2 srec[CAP];        // 22528 B
  __shared__ float tile[64][80];     // 20480 B
  __shared__ int shist[64], soff[64];

  if (t < 64) shist[t] = 0;
  __syncthreads();

  int cnt = cursor[g];
  if (cnt > CAP) cnt = CAP;
  const uint2* rec = sorted + (size_t)g * CAP;

  uint2 rr[3];
  int rk[3];
#pragma unroll
  for (int k = 0; k < 3; ++k) {
    const int idx = t + k * 1024;
    rk[k] = -1;
    if (idx < cnt) {
      rr[k] = rec[idx];                                  // coalesced
      rk[k] = atomicAdd(&shist[(rr[k].x >> 16) & 63], 1);
    }
  }
  __syncthreads();

  if (t < 64) {
    const int v = shist[t];
    int xx = v;
#pragma unroll
    for (int o = 1; o < 64; o <<= 1) {
      const int y = __shfl_up(xx, o, 64);
      if (t >= o) xx += y;
    }
    soff[t] = xx - v;
  }
  __syncthreads();

#pragma unroll
  for (int k = 0; k < 3; ++k) {
    if (rk[k] >= 0) {
      const int v = (rr[k].x >> 16) & 63;
      srec[soff[v] + rk[k]] = rr[k];
    }
  }
  __syncthreads();

  const int w = t >> 6;              // 16 waves
  const int l = t & 63;
  for (int j = 0; j < 4; ++j) {
    const int v = w * 4 + j;
    const int s0 = soff[v];
    const int n = shist[v];
    float a0 = 0.0f, a1 = 0.0f;
    int k = 0;
    for (; k + 4 <= n; k += 4) {
      const uint2 ra = srec[s0 + k + 0];   // broadcast ds_read
      const uint2 rb = srec[s0 + k + 1];
      const uint2 rc = srec[s0 + k + 2];
      const uint2 rd = srec[s0 + k + 3];
      const float* wa = ctxT + (size_t)(ra.x & 0xFFFFu) * C;
      const float* wb = ctxT + (size_t)(rb.x & 0xFFFFu) * C;
      const float* wc = ctxT + (size_t)(rc.x & 0xFFFFu) * C;
      const float* wd = ctxT + (size_t)(rd.x & 0xFFFFu) * C;
      const float pa = __uint_as_float(ra.y);
      const float pb = __uint_as_float(rb.y);
      const float pc = __uint_as_float(rc.y);
      const float pd = __uint_as_float(rd.y);
      a0 += pa * wa[l];
      a0 += pb * wb[l];
      a0 += pc * wc[l];
      a0 += pd * wd[l];
      if (l < 16) {
        a1 += pa * wa[64 + l];
        a1 += pb * wb[64 + l];
        a1 += pc * wc[64 + l];
        a1 += pd * wd[64 + l];
      }
    }
    for (; k < n; ++k) {
      const uint2 ra = srec[s0 + k];
      const float* wa = ctxT + (size_t)(ra.x & 0xFFFFu) * C;
      const float pa = __uint_as_float(ra.y);
      a0 += pa * wa[l];
      if (l < 16) a1 += pa * wa[64 + l];
    }
    tile[v][l] = a0;                 // exclusive ownership: plain writes
    if (l < 16) tile[v][64 + l] = a1;
  }
  __syncthreads();

  const size_t ob = (size_t)b * C * NV + vox0;
#pragma unroll
  for (int i = 0; i < 5; ++i) {
    const int idx = i * 1024 + t;
    const int c = idx >> 6;
    const int v = idx & 63;
    out[ob + (size_t)c * NV + v] = tile[v][c];
  }
}

// ---- fallback: direct channel-major atomics (out must be zeroed) ----
__global__ __launch_bounds__(256) void lift_splat_direct_kernel(
    const float* __restrict__ logits, const float* __restrict__ ctx,
    const int* __restrict__ gidx, float* __restrict__ out) {
  const int t = threadIdx.x;
  const int pix = blockIdx.x;
  const int hw = pix % HW;
  const int bn = pix / HW;
  const int b = bn / N;

  const float* lg = logits + (size_t)bn * DHW + hw;
  const int* gi = gidx + (size_t)bn * DHW + hw;
  const float* cx = ctx + (size_t)bn * (C * HW) + hw;

  __shared__ float s_prob[D];
  __shared__ float s_ctx[C];
  __shared__ int s_idx[D];
  __shared__ float red[256];

  float v = -3.0e38f;
  if (t < D) {
    v = lg[(size_t)t * HW];
    s_idx[t] = gi[(size_t)t * HW];
  }
  if (t < C) s_ctx[t] = cx[(size_t)t * HW];

  red[t] = v;
  __syncthreads();
#pragma unroll
  for (int s = 128; s >= 1; s >>= 1) {
    if (t < s) red[t] = fmaxf(red[t], red[t + s]);
    __syncthreads();
  }
  const float m = red[0];
  __syncthreads();

  const float e = (t < D) ? __expf(v - m) : 0.0f;
  red[t] = e;
  __syncthreads();
#pragma unroll
  for (int s = 128; s >= 1; s >>= 1) {
    if (t < s) red[t] += red[t + s];
    __syncthreads();
  }
  const float inv = 1.0f / red[0];
  if (t < D) s_prob[t] = e * inv;
  __syncthreads();

  for (int f = t; f < D * C; f += 256) {
    const int d = f / C;
    const int c = f - d * C;
    atomicAdd(&out[((size_t)(b * C + c)) * NV + s_idx[d]],
              s_prob[d] * s_ctx[c]);
  }
}

extern "C" void kernel_launch(void* const* d_in, const int* in_sizes, int n_in,
                              void* d_out, int out_size, void* d_ws,
                              size_t ws_size, hipStream_t stream) {
  const float* logits = (const float*)d_in[0];
  const float* ctx = (const float*)d_in[1];
  const int* gidx = (const int*)d_in[2];
  float* out = (float*)d_out;

  size_t off = 0;
  uint2* sorted = (uint2*)((char*)d_ws + off);
  off += (size_t)NBKT * CAP * sizeof(uint2);             // 11,534,336
  float* ctxT = (float*)((char*)d_ws + off);
  off += (size_t)NPIX * C * sizeof(float);               //  2,703,360
  int* cursor = (int*)((char*)d_ws + off);
  off += (size_t)NBKT * sizeof(int);                     // ~14.2 MB total

  if (ws_size >= off) {
    ctxT_kernel<<<NPIX / 64, 256, 0, stream>>>(ctx, ctxT, cursor);
    scatter_kernel<<<B * N * (HW / 16), 256, 0, stream>>>(logits, gidx,
                                                          cursor, sorted);
    gather_kernel<<<NBKT, 1024, 0, stream>>>(ctxT, sorted, cursor, out);
  } else {
    (void)hipMemsetAsync(d_out, 0, (size_t)out_size * sizeof(float), stream);
    lift_splat_direct_kernel<<<NPIX, 256, 0, stream>>>(logits, ctx, gidx, out);
  }
}